// Round 10
// baseline (87.630 us; speedup 1.0000x reference)
//
#include <hip/hip_runtime.h>

// VQ-VAE codebook: z [32,64,32,32] f32 NCHW, embedding [1024,64] f32.
// Outputs (concat, f32): z_q NCHW (2097152) | indices as float (32768) | loss (1).
// N = 32768 rows (n = b*1024 + hw), D = 64, K = 1024.
// dist(n,k) = sum_d z_d*(-2 e_kd) + (||e_k||^2 + 512)   [augmented e' rows]
//
// R10: R9 was LDS-pipe-bound (per-CU LDS pipe vs per-SIMD VALU: 24.6k vs
// 16.4k cyc/tile). za rows are contiguous in GLOBAL memory (z is d-major),
// so read za straight from L2 (8-way dup coalesces to 128 B/instr) and drop
// zt from LDS. Freed LDS double-buffers e' tiles (one barrier/tile, DMA
// prefetch issued before compute). LDS instr/dq halves -> VALU-bound.

#define DD 64
#define KK 1024
#define NROWS 32768
#define IDX_OFF 2097152
#define LOSS_OFF 2129920
#define BIGF 512.0f
#define RL 72                       // e' row length in floats (288 B)

__device__ __align__(16) float g_ep[KK * RL];      // augmented codebook
__device__ unsigned long long g_part[2][2][NROWS]; // [k-half][k-quarter][row]
__device__ float g_partial[512];                   // per-rowgroup loss partials

typedef const __attribute__((address_space(1))) void* gvp;
typedef __attribute__((address_space(3))) void* lvp;

__device__ __forceinline__ void gll16(const float* g, float* l) {
    __builtin_amdgcn_global_load_lds((gvp)(const void*)g, (lvp)(void*)l, 16, 0, 0);
}

// ---------------- kernel 0: build e' ---------------------------------------
__global__ __launch_bounds__(256) void vq_prep(const float* __restrict__ e) {
    int lane = threadIdx.x & 63;
    int k    = blockIdx.x * 4 + (threadIdx.x >> 6);
    float v  = e[k * DD + lane];
    float s  = v * v;
#pragma unroll
    for (int o = 32; o; o >>= 1) s += __shfl_xor(s, o, 64);
    float* row = g_ep + (size_t)k * RL;
    row[lane] = -2.0f * v;
    if (lane == 0)  row[64] = s + BIGF;
    if (lane >= 57) row[lane + 8] = 0.0f;   // cols 65..71
}

// ---------------- kernel 1: main — GEMM + fused argmin ---------------------
// grid 512: bid = h*256 + rg. Block: 256 thr (4 waves), 128 rows, k-half 512
// as 4 tiles of 128 ks, e' double-buffered in LDS. Wave w: row-half w&1,
// k-quarter w>>1. Lane: lr=lane>>3 (8 rows), lc=lane&7; acc[8][8] fragment.
// za operand comes from GLOBAL (L2): zg + d*1024 + rbase is contiguous.
__global__ __launch_bounds__(256, 2) void vq_main(const float* __restrict__ z) {
    __shared__ float et[2][128 * RL];  // 2 x 36.9 KB

    const int t    = threadIdx.x;
    const int lane = t & 63;
    const int w    = __builtin_amdgcn_readfirstlane(t >> 6);  // 0..3
    const int lr   = lane >> 3;
    const int lc   = lane & 7;
    const int bid  = blockIdx.x;
    const int rg   = bid & 255;        // rowgroup (128 rows)
    const int h    = bid >> 8;         // k-half
    const int q    = w >> 1;           // k-quarter owner (0/1)
    const int b    = rg >> 3;
    const int hw0  = (rg & 7) << 7;
    const int kb0  = h << 9;
    const int h64  = (w & 1) << 6;
    const int q64  = q << 6;
    const int rbase = h64 + lr * 8;

    const float* zw = z + (size_t)b * 65536 + hw0 + rbase;  // lane's 8-row base

    // ---- stage e' tile 0 (36 x 1 KB linear DMA, 9 per wave) ----
    {
        const float* src = g_ep + (size_t)kb0 * RL;
#pragma unroll
        for (int i = 0; i < 9; ++i) {
            int seg = w * 9 + i;
            gll16(src + seg * 256 + (lane << 2), &et[0][seg * 256]);
        }
    }

    float best[8];
    int   bi[8];
#pragma unroll
    for (int j = 0; j < 8; ++j) { best[j] = 3.4e38f; bi[j] = 0; }

    __syncthreads();   // drain DMA

    for (int tt = 0; tt < 4; ++tt) {
        const int cur = tt & 1;
        if (tt < 3) {                  // prefetch next tile into other buffer
            const float* src = g_ep + (size_t)(kb0 + ((tt + 1) << 7)) * RL;
#pragma unroll
            for (int i = 0; i < 9; ++i) {
                int seg = w * 9 + i;
                gll16(src + seg * 256 + (lane << 2), &et[cur ^ 1][seg * 256]);
            }
        }

        const float* etc = et[cur];
        // opaque per-tile copy: blocks LICM from hoisting za loads across
        // tiles (R2-R5 lesson: hoisted load-arrays get demoted/rematerialized)
        const float* zwt = zw;
        asm("" : "+v"(zwt));

        float acc[8][8];
#pragma unroll
        for (int j = 0; j < 8; ++j)
#pragma unroll
            for (int m = 0; m < 8; ++m) acc[j][m] = 0.f;

        // software-pipelined dq loop: za for dq+1 loads under dq's FMAs
        float zaP[4][8], zaN[4][8];
#pragma unroll
        for (int dd = 0; dd < 4; ++dd) {
            float4 a0 = *(const float4*)(zwt + (size_t)dd * 1024);
            float4 a1 = *(const float4*)(zwt + (size_t)dd * 1024 + 4);
            zaP[dd][0] = a0.x; zaP[dd][1] = a0.y; zaP[dd][2] = a0.z; zaP[dd][3] = a0.w;
            zaP[dd][4] = a1.x; zaP[dd][5] = a1.y; zaP[dd][6] = a1.z; zaP[dd][7] = a1.w;
        }

#pragma unroll 1
        for (int dq = 0; dq < 16; dq += 2) {
            // load za(dq+1)
#pragma unroll
            for (int dd = 0; dd < 4; ++dd) {
                const float* p = zwt + (size_t)((dq + 1) * 4 + dd) * 1024;
                float4 a0 = *(const float4*)p;
                float4 a1 = *(const float4*)(p + 4);
                zaN[dd][0] = a0.x; zaN[dd][1] = a0.y; zaN[dd][2] = a0.z; zaN[dd][3] = a0.w;
                zaN[dd][4] = a1.x; zaN[dd][5] = a1.y; zaN[dd][6] = a1.z; zaN[dd][7] = a1.w;
            }
            // FMA block dq (uses zaP)
#pragma unroll
            for (int m = 0; m < 8; ++m) {
                float4 ev = *(const float4*)&etc[(q64 + m * 8 + lc) * RL + (dq << 2)];
                float eb_[4] = {ev.x, ev.y, ev.z, ev.w};
#pragma unroll
                for (int dd = 0; dd < 4; ++dd)
#pragma unroll
                    for (int j = 0; j < 8; ++j)
                        acc[j][m] = fmaf(zaP[dd][j], eb_[dd], acc[j][m]);
            }
            // load za(dq+2)
            if (dq + 2 < 16) {
#pragma unroll
                for (int dd = 0; dd < 4; ++dd) {
                    const float* p = zwt + (size_t)((dq + 2) * 4 + dd) * 1024;
                    float4 a0 = *(const float4*)p;
                    float4 a1 = *(const float4*)(p + 4);
                    zaP[dd][0] = a0.x; zaP[dd][1] = a0.y; zaP[dd][2] = a0.z; zaP[dd][3] = a0.w;
                    zaP[dd][4] = a1.x; zaP[dd][5] = a1.y; zaP[dd][6] = a1.z; zaP[dd][7] = a1.w;
                }
            }
            // FMA block dq+1 (uses zaN)
#pragma unroll
            for (int m = 0; m < 8; ++m) {
                float4 ev = *(const float4*)&etc[(q64 + m * 8 + lc) * RL + ((dq + 1) << 2)];
                float eb_[4] = {ev.x, ev.y, ev.z, ev.w};
#pragma unroll
                for (int dd = 0; dd < 4; ++dd)
#pragma unroll
                    for (int j = 0; j < 8; ++j)
                        acc[j][m] = fmaf(zaN[dd][j], eb_[dd], acc[j][m]);
            }
        }

        // merge: cand = acc + (||e||^2 + 512)
        const int ktile = kb0 + (tt << 7);
#pragma unroll
        for (int m = 0; m < 8; ++m) {
            int kk = q64 + m * 8 + lc;
            float enorm = etc[kk * RL + 64];
#pragma unroll
            for (int j = 0; j < 8; ++j) {
                float cand = acc[j][m] + enorm;
                if (cand < best[j]) { best[j] = cand; bi[j] = ktile + kk; }
            }
        }
        __syncthreads();   // readers done with et[cur]; next tile's DMA visible
    }

    // cross-lane argmin over lc; u64 min => ties pick smallest k
#pragma unroll
    for (int j = 0; j < 8; ++j) {
        unsigned long long key =
            ((unsigned long long)__float_as_uint(best[j]) << 32) | (unsigned)bi[j];
#pragma unroll
        for (int o = 1; o < 8; o <<= 1) {
            unsigned long long other = __shfl_xor(key, o, 64);
            key = other < key ? other : key;
        }
        if (lc == 0)   // one writer per (h, q, row): no race
            g_part[h][q][(size_t)rg * 128 + rbase + j] = key;
    }
}

// ---------------- kernel 2: finalize — merge 4 partials, z_q, idx, loss ----
__global__ __launch_bounds__(256) void vq_fin(const float* __restrict__ z,
                                              const float* __restrict__ e,
                                              float* __restrict__ out) {
    __shared__ float lred[4];
    int lane = threadIdx.x & 63;
    int w    = threadIdx.x >> 6;
    int rg   = blockIdx.x;          // 0..511 rowgroups of 64
    int n    = rg * 64 + lane;
    int b    = rg >> 4;
    int hw0  = (rg & 15) << 6;

    unsigned long long k00 = g_part[0][0][n];
    unsigned long long k01 = g_part[0][1][n];
    unsigned long long k10 = g_part[1][0][n];
    unsigned long long k11 = g_part[1][1][n];
    unsigned long long key = k00;
    key = k01 < key ? k01 : key;
    key = k10 < key ? k10 : key;
    key = k11 < key ? k11 : key;    // u64 min: ties -> smallest k
    int idx = (int)(key & 0xFFFFFFFFull);
    if (w == 0) out[IDX_OFF + n] = (float)idx;

    const float*  zbase = z + (size_t)b * 65536 + hw0 + lane;
    float*        qbase = out + (size_t)b * 65536 + hw0 + lane;
    const float4* er4   = (const float4*)(e + (size_t)idx * 64) + (w << 2);

    float lsum = 0.f;
#pragma unroll
    for (int p = 0; p < 4; ++p) {
        float4 ev = er4[p];                        // gather, L2-resident
        int d = (w << 4) + (p << 2);
        float ezw[4] = {ev.x, ev.y, ev.z, ev.w};
#pragma unroll
        for (int qq = 0; qq < 4; ++qq) {
            float zv = zbase[(size_t)(d + qq) * 1024];
            float df = ezw[qq] - zv;
            lsum = fmaf(df, df, lsum);
            qbase[(size_t)(d + qq) * 1024] = ezw[qq]; // coalesced along hw
        }
    }
#pragma unroll
    for (int o = 32; o; o >>= 1) lsum += __shfl_xor(lsum, o, 64);
    if (lane == 0) lred[w] = lsum;
    __syncthreads();
    if (threadIdx.x == 0)
        g_partial[rg] = (lred[0] + lred[1]) + (lred[2] + lred[3]);
}

// ---------------- kernel 3: loss scalar ------------------------------------
__global__ __launch_bounds__(64) void vq_finish(float* __restrict__ out) {
    int lane = threadIdx.x;
    float s = 0.f;
#pragma unroll
    for (int i = 0; i < 8; ++i) s += g_partial[lane * 8 + i];
#pragma unroll
    for (int o = 32; o; o >>= 1) s += __shfl_xor(s, o, 64);
    // loss = q_latent + 0.25*e_latent = 1.25 * mean((z_q - z)^2)
    if (lane == 0) out[LOSS_OFF] = s * (1.25f / 2097152.0f);
}

extern "C" void kernel_launch(void* const* d_in, const int* in_sizes, int n_in,
                              void* d_out, int out_size, void* d_ws, size_t ws_size,
                              hipStream_t stream) {
    const float* z = (const float*)d_in[0];
    const float* e = (const float*)d_in[1];
    float* out = (float*)d_out;

    vq_prep<<<256, 256, 0, stream>>>(e);
    vq_main<<<512, 256, 0, stream>>>(z);
    vq_fin<<<512, 256, 0, stream>>>(z, e, out);
    vq_finish<<<1, 64, 0, stream>>>(out);
}

// Round 11
// 81.892 us; speedup vs baseline: 1.0701x; 1.0701x over previous
//
#include <hip/hip_runtime.h>

// VQ-VAE codebook: z [32,64,32,32] f32 NCHW, embedding [1024,64] f32.
// Outputs (concat, f32): z_q NCHW (2097152) | indices as float (32768) | loss (1).
// N = 32768 rows (n = b*1024 + hw), D = 64, K = 1024.
//
// R11: MFMA screen + exact re-verify. R9/R10 showed fp32-VALU GEMM is capped
// ~60 us by per-CU operand delivery (LDS ~85 B/cyc, L1 ~64 B/cyc). Screen:
// d~ = sum_d [zh*ehm + zh*elm + zl*ehm] + (||e||^2+512) via 6 bf16 MFMAs per
// 16x16 tile (eps ~1e-4 << typical top-2 gap ~6). Track per-lane top-2 keys,
// extract row top-3 by d~, then vq_fin re-evaluates those 3 in exact fp32
// (identical formula to the R9 kernel that passed) -> exact argmin, ties ->
// smallest k (u64 key packing). z_q / loss exact as before.

#define IDX_OFF 2097152
#define LOSS_OFF 2129920
#define BIGF 512.0f
#define RL 72
#define U64INF 0xFFFFFFFFFFFFFFFFull

typedef __attribute__((ext_vector_type(8))) short bf16x8;
typedef __attribute__((ext_vector_type(4))) float f32x4;

__device__ __align__(256) float g_ep[1024 * RL];        // [-2e | ||e||^2+512 | pad]
__device__ __align__(256) unsigned short g_ehm[1024 * 64]; // bf16(-2e)
__device__ __align__(256) unsigned short g_elm[1024 * 64]; // bf16(-2e - ehm)
__device__ unsigned long long g_top[32768][4];          // top-3 screen keys per row
__device__ float g_partial[512];

__device__ __forceinline__ unsigned int f2bf(float f) {   // fp32 -> bf16 bits, RTN-even
    unsigned int u = __float_as_uint(f);
    return (u + 0x7FFFu + ((u >> 16) & 1u)) >> 16;
}

__device__ __forceinline__ unsigned long long min16(unsigned long long x) {
#pragma unroll
    for (int o = 1; o < 16; o <<= 1) {
        unsigned long long y = __shfl_xor(x, o, 64);
        x = y < x ? y : x;
    }
    return x;
}

// ---------------- kernel 0: build e', ehm, elm -----------------------------
__global__ __launch_bounds__(256) void vq_prep(const float* __restrict__ e) {
    int lane = threadIdx.x & 63;
    int k    = blockIdx.x * 4 + (threadIdx.x >> 6);
    float v  = e[k * 64 + lane];
    float m2 = -2.0f * v;
    float s  = v * v;
#pragma unroll
    for (int o = 32; o; o >>= 1) s += __shfl_xor(s, o, 64);
    g_ep[(size_t)k * RL + lane] = m2;
    if (lane == 0) g_ep[(size_t)k * RL + 64] = s + BIGF;
    unsigned hb = f2bf(m2);
    float    hf = __uint_as_float(hb << 16);
    unsigned lb = f2bf(m2 - hf);
    g_ehm[(size_t)k * 64 + lane] = (unsigned short)hb;
    g_elm[(size_t)k * 64 + lane] = (unsigned short)lb;
}

// ---------------- kernel 1: MFMA screen ------------------------------------
// grid 512: 64 rows/block, 4 waves; wave w owns rows w*16..w*16+15.
// A-frag (z rows): lane holds A[row=lane&15][k=(lane>>4)*8+j]; B-frag (codes):
// lane holds B[k=(lane>>4)*8+j][col=lane&15] = ehm[col][k]; C/D (m89-verified):
// col=lane&15, row=(lane>>4)*4+reg.
__global__ __launch_bounds__(256, 2) void vq_main(const float* __restrict__ z) {
    __shared__ float enb[1024];

    const int t    = threadIdx.x;
    const int lane = t & 63;
    const int w    = __builtin_amdgcn_readfirstlane(t >> 6);  // 0..3
    const int col  = lane & 15;
    const int g4   = lane >> 4;       // 0..3
    const int bid  = blockIdx.x;      // 0..511
    const int b    = bid >> 4;
    const int hw0  = (bid & 15) << 6;

    // stage enb (||e||^2 + 512) into LDS
#pragma unroll
    for (int i = 0; i < 4; ++i) {
        int kk = t * 4 + i;
        enb[kk] = g_ep[(size_t)kk * RL + 64];
    }

    // build A-fragments: zh/zl for this lane's row, both 32-d chunks
    const float* zr = z + (size_t)b * 65536 + hw0 + (w * 16 + col);
    bf16x8 zh[2], zl[2];
#pragma unroll
    for (int c = 0; c < 2; ++c)
#pragma unroll
        for (int j = 0; j < 8; ++j) {
            int d = c * 32 + g4 * 8 + j;
            float f = zr[(size_t)d * 1024];
            unsigned hb = f2bf(f);
            float    hf = __uint_as_float(hb << 16);
            unsigned lb = f2bf(f - hf);
            zh[c][j] = (short)hb;
            zl[c][j] = (short)lb;
        }
    __syncthreads();

    unsigned long long t0[4], t1[4];
#pragma unroll
    for (int r = 0; r < 4; ++r) { t0[r] = U64INF; t1[r] = U64INF; }

#pragma unroll 2
    for (int g = 0; g < 64; ++g) {
        int kc = g * 16 + col;
        const bf16x8* ph = (const bf16x8*)(g_ehm + (size_t)kc * 64);
        const bf16x8* pl = (const bf16x8*)(g_elm + (size_t)kc * 64);
        bf16x8 eh0 = ph[g4];       // chunk 0: elems (g4*8..)
        bf16x8 eh1 = ph[4 + g4];   // chunk 1: elems 32 + (g4*8..)
        bf16x8 el0 = pl[g4];
        bf16x8 el1 = pl[4 + g4];

        f32x4 acc = {0.f, 0.f, 0.f, 0.f};
        acc = __builtin_amdgcn_mfma_f32_16x16x32_bf16(zh[0], eh0, acc, 0, 0, 0);
        acc = __builtin_amdgcn_mfma_f32_16x16x32_bf16(zh[1], eh1, acc, 0, 0, 0);
        acc = __builtin_amdgcn_mfma_f32_16x16x32_bf16(zh[0], el0, acc, 0, 0, 0);
        acc = __builtin_amdgcn_mfma_f32_16x16x32_bf16(zh[1], el1, acc, 0, 0, 0);
        acc = __builtin_amdgcn_mfma_f32_16x16x32_bf16(zl[0], eh0, acc, 0, 0, 0);
        acc = __builtin_amdgcn_mfma_f32_16x16x32_bf16(zl[1], eh1, acc, 0, 0, 0);

        float enbv = enb[kc];
#pragma unroll
        for (int r = 0; r < 4; ++r) {
            float cand = acc[r] + enbv;        // > 0 (bias 512) -> uint order ok
            unsigned long long key =
                ((unsigned long long)__float_as_uint(cand) << 32) | (unsigned)kc;
            unsigned long long nt1 = key < t0[r] ? t0[r] : (key < t1[r] ? key : t1[r]);
            unsigned long long nt0 = key < t0[r] ? key : t0[r];
            t0[r] = nt0; t1[r] = nt1;
        }
    }

    // per row (16-lane group g4): extract global top-3 by screen key
#pragma unroll
    for (int r = 0; r < 4; ++r) {
        unsigned long long a = t0[r], bb = t1[r];
        unsigned long long m1 = min16(a);
        if (a == m1) { a = bb; bb = U64INF; }   // keys unique (k in low bits)
        unsigned long long m2 = min16(a);
        if (a == m2) { a = bb; bb = U64INF; }
        unsigned long long m3 = min16(a);
        int n = bid * 64 + w * 16 + g4 * 4 + r;
        if (col == 0) g_top[n][0] = m1;
        if (col == 1) g_top[n][1] = m2;
        if (col == 2) g_top[n][2] = m3;
    }
}

// ---------------- kernel 2: exact re-verify + z_q + idx + loss -------------
__global__ __launch_bounds__(256) void vq_fin(const float* __restrict__ z,
                                              const float* __restrict__ e,
                                              float* __restrict__ out) {
    __shared__ float sred[4][64][3];
    __shared__ int   ishare[64];
    __shared__ float lred[4];
    int lane = threadIdx.x & 63;
    int w    = threadIdx.x >> 6;
    int rg   = blockIdx.x;          // 0..511 rowgroups of 64
    int n    = rg * 64 + lane;
    int b    = rg >> 4;
    int hw0  = (rg & 15) << 6;

    int k0 = (int)(g_top[n][0] & 0xFFFFFFFFull);
    int k1 = (int)(g_top[n][1] & 0xFFFFFFFFull);
    int k2 = (int)(g_top[n][2] & 0xFFFFFFFFull);

    const float* zbase = z + (size_t)b * 65536 + hw0 + lane;
    const float* e0 = g_ep + (size_t)k0 * RL;
    const float* e1 = g_ep + (size_t)k1 * RL;
    const float* e2 = g_ep + (size_t)k2 * RL;

    // exact partial dots over this wave's d-range (fp32, g_ep = -2e)
    float p0 = 0.f, p1 = 0.f, p2 = 0.f;
#pragma unroll
    for (int j = 0; j < 16; ++j) {
        int d = w * 16 + j;
        float zv = zbase[(size_t)d * 1024];
        p0 = fmaf(zv, e0[d], p0);
        p1 = fmaf(zv, e1[d], p1);
        p2 = fmaf(zv, e2[d], p2);
    }
    sred[w][lane][0] = p0; sred[w][lane][1] = p1; sred[w][lane][2] = p2;
    __syncthreads();

    if (w == 0) {
        float d0 = sred[0][lane][0] + sred[1][lane][0] + sred[2][lane][0] + sred[3][lane][0]
                 + g_ep[(size_t)k0 * RL + 64];
        float d1 = sred[0][lane][1] + sred[1][lane][1] + sred[2][lane][1] + sred[3][lane][1]
                 + g_ep[(size_t)k1 * RL + 64];
        float d2 = sred[0][lane][2] + sred[1][lane][2] + sred[2][lane][2] + sred[3][lane][2]
                 + g_ep[(size_t)k2 * RL + 64];
        unsigned long long ky0 = ((unsigned long long)__float_as_uint(d0) << 32) | (unsigned)k0;
        unsigned long long ky1 = ((unsigned long long)__float_as_uint(d1) << 32) | (unsigned)k1;
        unsigned long long ky2 = ((unsigned long long)__float_as_uint(d2) << 32) | (unsigned)k2;
        unsigned long long ky = ky0;
        ky = ky1 < ky ? ky1 : ky;
        ky = ky2 < ky ? ky2 : ky;        // exact min; ties -> smallest k
        int idx = (int)(ky & 0xFFFFFFFFull);
        out[IDX_OFF + n] = (float)idx;
        ishare[lane] = idx;
    }
    __syncthreads();

    int idx = ishare[lane];
    float*        qbase = out + (size_t)b * 65536 + hw0 + lane;
    const float4* er4   = (const float4*)(e + (size_t)idx * 64) + (w << 2);

    float lsum = 0.f;
#pragma unroll
    for (int p = 0; p < 4; ++p) {
        float4 ev = er4[p];                        // gather, L2-resident
        int d = (w << 4) + (p << 2);
        float ezw[4] = {ev.x, ev.y, ev.z, ev.w};
#pragma unroll
        for (int qq = 0; qq < 4; ++qq) {
            float zv = zbase[(size_t)(d + qq) * 1024];
            float df = ezw[qq] - zv;
            lsum = fmaf(df, df, lsum);
            qbase[(size_t)(d + qq) * 1024] = ezw[qq]; // coalesced along hw
        }
    }
#pragma unroll
    for (int o = 32; o; o >>= 1) lsum += __shfl_xor(lsum, o, 64);
    if (lane == 0) lred[w] = lsum;
    __syncthreads();
    if (threadIdx.x == 0)
        g_partial[rg] = (lred[0] + lred[1]) + (lred[2] + lred[3]);
}

// ---------------- kernel 3: loss scalar ------------------------------------
__global__ __launch_bounds__(64) void vq_finish(float* __restrict__ out) {
    int lane = threadIdx.x;
    float s = 0.f;
#pragma unroll
    for (int i = 0; i < 8; ++i) s += g_partial[lane * 8 + i];
#pragma unroll
    for (int o = 32; o; o >>= 1) s += __shfl_xor(s, o, 64);
    // loss = q_latent + 0.25*e_latent = 1.25 * mean((z_q - z)^2)
    if (lane == 0) out[LOSS_OFF] = s * (1.25f / 2097152.0f);
}

extern "C" void kernel_launch(void* const* d_in, const int* in_sizes, int n_in,
                              void* d_out, int out_size, void* d_ws, size_t ws_size,
                              hipStream_t stream) {
    const float* z = (const float*)d_in[0];
    const float* e = (const float*)d_in[1];
    float* out = (float*)d_out;

    vq_prep<<<256, 256, 0, stream>>>(e);
    vq_main<<<512, 256, 0, stream>>>(z);
    vq_fin<<<512, 256, 0, stream>>>(z, e, out);
    vq_finish<<<1, 64, 0, stream>>>(out);
}

// Round 12
// 41.476 us; speedup vs baseline: 2.1128x; 1.9744x over previous
//
#include <hip/hip_runtime.h>

// VQ-VAE codebook: z [32,64,32,32] f32 NCHW, embedding [1024,64] f32.
// Outputs (concat, f32): z_q NCHW (2097152) | indices as float (32768) | loss (1).
//
// R12: R11's MFMA screen was latency-bound on per-lane B-frag global loads
// (VGPR=40 -> no pipeline depth). Fix: prep pre-packs B-fragments in lane
// order (g_bf[g][frag][lane][j]) so staging is linear gll16 DMA and the k-loop
// reads frags as contiguous ds_read_b128 (conflict-free), double-buffered
// 8-group tiles. Math/reduction identical to R11 (passed): 3-term bf16 split
// screen -> row top-3 by screen key -> exact fp32 re-verify in vq_fin.

#define IDX_OFF 2097152
#define LOSS_OFF 2129920
#define BIGF 512.0f
#define RL 72
#define U64INF 0xFFFFFFFFFFFFFFFFull

typedef __attribute__((ext_vector_type(8))) short bf16x8;
typedef __attribute__((ext_vector_type(4))) float f32x4;

__device__ __align__(256) float g_ep[1024 * RL];     // [-2e | ||e||^2+512 | pad]
__device__ __align__(256) float g_enb[1024];         // dense ||e||^2+512
__device__ __align__(256) unsigned short g_bf[64 * 4 * 64 * 8]; // [g][f][lane][j]
__device__ unsigned long long g_top[32768][4];       // top-3 screen keys per row
__device__ float g_partial[512];

typedef const __attribute__((address_space(1))) void* gvp;
typedef __attribute__((address_space(3))) void* lvp;

__device__ __forceinline__ void gll16(const void* g, void* l) {
    __builtin_amdgcn_global_load_lds((gvp)g, (lvp)l, 16, 0, 0);
}

__device__ __forceinline__ unsigned int f2bf(float f) {   // fp32 -> bf16, RTN-even
    unsigned int u = __float_as_uint(f);
    return (u + 0x7FFFu + ((u >> 16) & 1u)) >> 16;
}

__device__ __forceinline__ unsigned long long min16(unsigned long long x) {
#pragma unroll
    for (int o = 1; o < 16; o <<= 1) {
        unsigned long long y = __shfl_xor(x, o, 64);
        x = y < x ? y : x;
    }
    return x;
}

// ---------------- kernel 0: build e', enb, packed B-frags ------------------
// B-frag layout (from R11, verified): for group g, lane l (col=l&15, g4=l>>4):
// frag f=0: ehm[g*16+col][g4*8+j]      f=1: ehm[..][32+g4*8+j]
// frag f=2: elm[g*16+col][g4*8+j]      f=3: elm[..][32+g4*8+j]
// Stored at g_bf[((g*4+f)*64 + l)*8 + j] -> staging & ds_read are linear.
__global__ __launch_bounds__(256) void vq_prep(const float* __restrict__ e) {
    int lane = threadIdx.x & 63;
    int k    = blockIdx.x * 4 + (threadIdx.x >> 6);
    float v  = e[k * 64 + lane];
    float m2 = -2.0f * v;
    float s  = v * v;
#pragma unroll
    for (int o = 32; o; o >>= 1) s += __shfl_xor(s, o, 64);
    g_ep[(size_t)k * RL + lane] = m2;
    if (lane == 0) { g_ep[(size_t)k * RL + 64] = s + BIGF; g_enb[k] = s + BIGF; }
    unsigned hb = f2bf(m2);
    float    hf = __uint_as_float(hb << 16);
    unsigned lb = f2bf(m2 - hf);
    int g  = k >> 4, c = k & 15;
    int ch = lane >> 5, dc = lane & 31;
    int g4 = dc >> 3,  j = dc & 7;
    int l  = g4 * 16 + c;
    g_bf[(size_t)((g * 4 + ch) * 64 + l) * 8 + j]     = (unsigned short)hb;
    g_bf[(size_t)((g * 4 + 2 + ch) * 64 + l) * 8 + j] = (unsigned short)lb;
}

// ---------------- kernel 1: MFMA screen ------------------------------------
// grid 512: 64 rows/block, 4 waves; wave w owns rows w*16..w*16+15.
// B-frag tiles (8 groups = 32 KB) double-buffered in LDS via linear DMA.
__global__ __launch_bounds__(256, 2) void vq_main(const float* __restrict__ z) {
    __shared__ float enb[1024];
    __shared__ unsigned short bf[2][8 * 2048];   // 2 x 32 KB

    const int t    = threadIdx.x;
    const int lane = t & 63;
    const int w    = __builtin_amdgcn_readfirstlane(t >> 6);  // 0..3
    const int col  = lane & 15;
    const int g4   = lane >> 4;
    const int bid  = blockIdx.x;      // 0..511
    const int b    = bid >> 4;
    const int hw0  = (bid & 15) << 6;

    // stage enb (4 KB) + B-tile 0 (32 KB) via linear DMA
    gll16((const char*)g_enb + w * 1024 + lane * 16, (char*)enb + w * 1024);
#pragma unroll
    for (int i = 0; i < 8; ++i) {
        int seg = w * 8 + i;
        gll16((const char*)g_bf + seg * 1024 + lane * 16, (char*)&bf[0][0] + seg * 1024);
    }

    // A-fragments: zh/zl for this lane's row (computed -> stays in VGPRs)
    const float* zr = z + (size_t)b * 65536 + hw0 + (w * 16 + col);
    bf16x8 zh[2], zl[2];
#pragma unroll
    for (int c = 0; c < 2; ++c)
#pragma unroll
        for (int j = 0; j < 8; ++j) {
            int d = c * 32 + g4 * 8 + j;
            float f = zr[(size_t)d * 1024];
            unsigned hb = f2bf(f);
            float    hf = __uint_as_float(hb << 16);
            unsigned lb = f2bf(f - hf);
            zh[c][j] = (short)hb;
            zl[c][j] = (short)lb;
        }

    unsigned long long t0[4], t1[4];
#pragma unroll
    for (int r = 0; r < 4; ++r) { t0[r] = U64INF; t1[r] = U64INF; }

    __syncthreads();   // DMA drained (vmcnt) -> tile 0 + enb visible

    for (int tt = 0; tt < 8; ++tt) {
        const int cur = tt & 1;
        if (tt < 7) {   // prefetch next tile into other buffer (fire-and-forget)
#pragma unroll
            for (int i = 0; i < 8; ++i) {
                int seg = w * 8 + i;
                gll16((const char*)g_bf + (tt + 1) * 32768 + seg * 1024 + lane * 16,
                      (char*)&bf[cur ^ 1][0] + seg * 1024);
            }
        }

        const unsigned short* bfc = &bf[cur][0];
#pragma unroll
        for (int gg = 0; gg < 8; ++gg) {
            const int g  = tt * 8 + gg;
            const int kc = g * 16 + col;
            const bf16x8* p = (const bf16x8*)(bfc + gg * 2048);
            bf16x8 eh0 = p[0 * 64 + lane];   // ds_read_b128, contiguous: no conflicts
            bf16x8 eh1 = p[1 * 64 + lane];
            bf16x8 el0 = p[2 * 64 + lane];
            bf16x8 el1 = p[3 * 64 + lane];

            f32x4 acc = {0.f, 0.f, 0.f, 0.f};
            acc = __builtin_amdgcn_mfma_f32_16x16x32_bf16(zh[0], eh0, acc, 0, 0, 0);
            acc = __builtin_amdgcn_mfma_f32_16x16x32_bf16(zh[1], eh1, acc, 0, 0, 0);
            acc = __builtin_amdgcn_mfma_f32_16x16x32_bf16(zh[0], el0, acc, 0, 0, 0);
            acc = __builtin_amdgcn_mfma_f32_16x16x32_bf16(zh[1], el1, acc, 0, 0, 0);
            acc = __builtin_amdgcn_mfma_f32_16x16x32_bf16(zl[0], eh0, acc, 0, 0, 0);
            acc = __builtin_amdgcn_mfma_f32_16x16x32_bf16(zl[1], eh1, acc, 0, 0, 0);

            float enbv = enb[kc];
#pragma unroll
            for (int r = 0; r < 4; ++r) {
                float cand = acc[r] + enbv;      // > 0 (bias) -> uint order = float order
                unsigned long long key =
                    ((unsigned long long)__float_as_uint(cand) << 32) | (unsigned)kc;
                unsigned long long nt1 = key < t0[r] ? t0[r] : (key < t1[r] ? key : t1[r]);
                unsigned long long nt0 = key < t0[r] ? key : t0[r];
                t0[r] = nt0; t1[r] = nt1;
            }
        }
        __syncthreads();   // readers done with bf[cur]; next tile's DMA drained
    }

    // per row (16-lane group): extract global top-3 by screen key
#pragma unroll
    for (int r = 0; r < 4; ++r) {
        unsigned long long a = t0[r], bb = t1[r];
        unsigned long long m1 = min16(a);
        if (a == m1) { a = bb; bb = U64INF; }   // keys unique (k in low bits)
        unsigned long long m2 = min16(a);
        if (a == m2) { a = bb; bb = U64INF; }
        unsigned long long m3 = min16(a);
        int n = bid * 64 + w * 16 + g4 * 4 + r;
        if (col == 0) g_top[n][0] = m1;
        if (col == 1) g_top[n][1] = m2;
        if (col == 2) g_top[n][2] = m3;
    }
}

// ---------------- kernel 2: exact re-verify + z_q + idx + loss -------------
__global__ __launch_bounds__(256) void vq_fin(const float* __restrict__ z,
                                              const float* __restrict__ e,
                                              float* __restrict__ out) {
    __shared__ float sred[4][64][3];
    __shared__ int   ishare[64];
    __shared__ float lred[4];
    int lane = threadIdx.x & 63;
    int w    = threadIdx.x >> 6;
    int rg   = blockIdx.x;          // 0..511 rowgroups of 64
    int n    = rg * 64 + lane;
    int b    = rg >> 4;
    int hw0  = (rg & 15) << 6;

    int k0 = (int)(g_top[n][0] & 0xFFFFFFFFull);
    int k1 = (int)(g_top[n][1] & 0xFFFFFFFFull);
    int k2 = (int)(g_top[n][2] & 0xFFFFFFFFull);

    const float* zbase = z + (size_t)b * 65536 + hw0 + lane;
    const float* e0 = g_ep + (size_t)k0 * RL;
    const float* e1 = g_ep + (size_t)k1 * RL;
    const float* e2 = g_ep + (size_t)k2 * RL;

    float p0 = 0.f, p1 = 0.f, p2 = 0.f;
#pragma unroll
    for (int j = 0; j < 16; ++j) {
        int d = w * 16 + j;
        float zv = zbase[(size_t)d * 1024];
        p0 = fmaf(zv, e0[d], p0);
        p1 = fmaf(zv, e1[d], p1);
        p2 = fmaf(zv, e2[d], p2);
    }
    sred[w][lane][0] = p0; sred[w][lane][1] = p1; sred[w][lane][2] = p2;
    __syncthreads();

    if (w == 0) {
        float d0 = sred[0][lane][0] + sred[1][lane][0] + sred[2][lane][0] + sred[3][lane][0]
                 + g_ep[(size_t)k0 * RL + 64];
        float d1 = sred[0][lane][1] + sred[1][lane][1] + sred[2][lane][1] + sred[3][lane][1]
                 + g_ep[(size_t)k1 * RL + 64];
        float d2 = sred[0][lane][2] + sred[1][lane][2] + sred[2][lane][2] + sred[3][lane][2]
                 + g_ep[(size_t)k2 * RL + 64];
        unsigned long long ky0 = ((unsigned long long)__float_as_uint(d0) << 32) | (unsigned)k0;
        unsigned long long ky1 = ((unsigned long long)__float_as_uint(d1) << 32) | (unsigned)k1;
        unsigned long long ky2 = ((unsigned long long)__float_as_uint(d2) << 32) | (unsigned)k2;
        unsigned long long ky = ky0;
        ky = ky1 < ky ? ky1 : ky;
        ky = ky2 < ky ? ky2 : ky;        // exact min; ties -> smallest k
        int idx = (int)(ky & 0xFFFFFFFFull);
        out[IDX_OFF + n] = (float)idx;
        ishare[lane] = idx;
    }
    __syncthreads();

    int idx = ishare[lane];
    float*        qbase = out + (size_t)b * 65536 + hw0 + lane;
    const float4* er4   = (const float4*)(e + (size_t)idx * 64) + (w << 2);

    float lsum = 0.f;
#pragma unroll
    for (int p = 0; p < 4; ++p) {
        float4 ev = er4[p];                        // gather, L2-resident
        int d = (w << 4) + (p << 2);
        float ezw[4] = {ev.x, ev.y, ev.z, ev.w};
#pragma unroll
        for (int qq = 0; qq < 4; ++qq) {
            float zv = zbase[(size_t)(d + qq) * 1024];
            float df = ezw[qq] - zv;
            lsum = fmaf(df, df, lsum);
            qbase[(size_t)(d + qq) * 1024] = ezw[qq]; // coalesced along hw
        }
    }
#pragma unroll
    for (int o = 32; o; o >>= 1) lsum += __shfl_xor(lsum, o, 64);
    if (lane == 0) lred[w] = lsum;
    __syncthreads();
    if (threadIdx.x == 0)
        g_partial[rg] = (lred[0] + lred[1]) + (lred[2] + lred[3]);
}

// ---------------- kernel 3: loss scalar ------------------------------------
__global__ __launch_bounds__(64) void vq_finish(float* __restrict__ out) {
    int lane = threadIdx.x;
    float s = 0.f;
#pragma unroll
    for (int i = 0; i < 8; ++i) s += g_partial[lane * 8 + i];
#pragma unroll
    for (int o = 32; o; o >>= 1) s += __shfl_xor(s, o, 64);
    // loss = q_latent + 0.25*e_latent = 1.25 * mean((z_q - z)^2)
    if (lane == 0) out[LOSS_OFF] = s * (1.25f / 2097152.0f);
}

extern "C" void kernel_launch(void* const* d_in, const int* in_sizes, int n_in,
                              void* d_out, int out_size, void* d_ws, size_t ws_size,
                              hipStream_t stream) {
    const float* z = (const float*)d_in[0];
    const float* e = (const float*)d_in[1];
    float* out = (float*)d_out;

    vq_prep<<<256, 256, 0, stream>>>(e);
    vq_main<<<512, 256, 0, stream>>>(z);
    vq_fin<<<512, 256, 0, stream>>>(z, e, out);
    vq_finish<<<1, 64, 0, stream>>>(out);
}